// Round 6
// baseline (435.056 us; speedup 1.0000x reference)
//
#include <hip/hip_runtime.h>

#define NROW 16384
#define DDIM 128
#define KHALF 8192
#define ITERS (KHALF / 64)

typedef _Float16 f16x8 __attribute__((ext_vector_type(8)));
typedef float f32x4 __attribute__((ext_vector_type(4)));
typedef float f32x16 __attribute__((ext_vector_type(16)));

__device__ __forceinline__ unsigned short f2h(float x) {
  union { _Float16 f; unsigned short u; } cvt;
  cvt.f = (_Float16)x;  // RNE
  return cvt.u;
}

// Raw barrier without vmcnt(0) drain (prefetch stays in flight).
__device__ __forceinline__ void block_sync() {
  asm volatile("s_waitcnt lgkmcnt(0)" ::: "memory");
  __builtin_amdgcn_s_barrier();
  asm volatile("" ::: "memory");
}

// ---------------- prep: hq[k>>3][d][k&7] = fp16(h[k][d]) ----------------
__global__ __launch_bounds__(256) void prep_hq(const float* __restrict__ h,
                                               unsigned short* __restrict__ hq) {
  __shared__ unsigned short tile[DDIM][65];
  const int t = threadIdx.x;
  const int k0 = blockIdx.x * 64;
#pragma unroll
  for (int rep = 0; rep < 8; ++rep) {
    int idx = rep * 256 + t;
    int r = idx >> 5, c4 = idx & 31;
    const float4 v = *(const float4*)(h + (size_t)(k0 + r) * DDIM + c4 * 4);
    int c = c4 * 4;
    tile[c + 0][r] = f2h(v.x);
    tile[c + 1][r] = f2h(v.y);
    tile[c + 2][r] = f2h(v.z);
    tile[c + 3][r] = f2h(v.w);
  }
  __syncthreads();
#pragma unroll
  for (int rep = 0; rep < 4; ++rep) {
    int idx = rep * 256 + t;          // c = idx>>7 (chunk), d = idx&127
    int c = idx >> 7, d = idx & 127;
    int ko = c * 8;
    uint4 o;
    o.x = (unsigned)tile[d][ko + 0] | ((unsigned)tile[d][ko + 1] << 16);
    o.y = (unsigned)tile[d][ko + 2] | ((unsigned)tile[d][ko + 3] << 16);
    o.z = (unsigned)tile[d][ko + 4] | ((unsigned)tile[d][ko + 5] << 16);
    o.w = (unsigned)tile[d][ko + 6] | ((unsigned)tile[d][ko + 7] << 16);
    *(uint4*)(hq + (size_t)k0 * DDIM + idx * 8) = o;
  }
}

// ---------------- fused partial: block (rt, kh) ----------------
// BM=64 rows, k in [kh*8192, +8192). 256 threads = 4 waves, wave w owns
// k-chunk w*16 of each 64-k tile (k-split; A,B each LDS-read exactly once).
// A: coalesced fp32 load -> exp -> fp16 -> XOR-swizzled LDS (dbuf 2x8KB).
// B: hq tile 16KB contiguous -> linear LDS (dbuf 2x16KB).
// One raw barrier per iter. Partials + rowsum partials to workspace.
__global__ __launch_bounds__(256, 2) void fused(const float* __restrict__ adj,
                                                const unsigned short* __restrict__ hq,
                                                float* __restrict__ ppart,
                                                float* __restrict__ rspart) {
  __shared__ __align__(16) char smem[49152];  // A: 2*8KB @0, B: 2*16KB @16384
  const int t = threadIdx.x;
  const int l = t & 63, w = t >> 6;
  const int rt = blockIdx.x >> 1, kh = blockIdx.x & 1;
  const size_t m0 = (size_t)rt * 64;

  // A staging: thread t, instr j covers row j*16+(t>>4), k-bytes (t&15)*16
  const float* asrc = adj + (m0 + (t >> 4)) * (size_t)NROW + kh * KHALF + (t & 15) * 4;
  // A LDS write: fp16 8B piece at chunk c=(t&15)>>1, half=(t&15)&1; row&7 == (t>>4)&7
  const int awoff = (t >> 4) * 128 + ((((t & 15) >> 1) ^ ((t >> 4) & 7)) << 4) +
                    ((t & 1) << 3);
  // B staging: 16KB contiguous tile, thread t instr j at byte j*4096 + t*16
  const unsigned short* qbase = hq + (size_t)kh * (KHALF * DDIM) + t * 8;

  // fragment read offsets (validated mappings from R5)
  const int row_l = l & 31, hh = l >> 5;
  const int cc = w * 2 + hh;                         // local k-chunk 0..7
  const int aro0 = row_l * 128 + ((cc ^ (row_l & 7)) << 4);
  const int aro1 = aro0 + 32 * 128;
  const int bro = cc * 2048 + row_l * 16;            // + cg*512

  f32x16 acc[2][4];
#pragma unroll
  for (int rg = 0; rg < 2; ++rg)
#pragma unroll
    for (int cg = 0; cg < 4; ++cg)
#pragma unroll
      for (int e = 0; e < 16; ++e) acc[rg][cg][e] = 0.f;
  float rs4[4] = {0.f, 0.f, 0.f, 0.f};

  float4 pa[4];
  uint4 pq[4];
#pragma unroll
  for (int j = 0; j < 4; ++j) {
    pa[j] = *(const float4*)(asrc + (size_t)j * 16 * NROW);
    pq[j] = *(const uint4*)(qbase + j * 2048);
  }

  for (int it = 0; it < ITERS; ++it) {
    const int cur = it & 1;
    char* abuf = smem + cur * 8192;
    char* bbuf = smem + 16384 + cur * 16384;

    // A: exp + pack + rowsum partial + swizzled LDS write
#pragma unroll
    for (int j = 0; j < 4; ++j) {
      const float4 v = pa[j];
      const float e0 = __expf(v.x), e1 = __expf(v.y);
      const float e2 = __expf(v.z), e3 = __expf(v.w);
      rs4[j] += (e0 + e1) + (e2 + e3);
      uint2 pk;
      pk.x = (unsigned)f2h(e0) | ((unsigned)f2h(e1) << 16);
      pk.y = (unsigned)f2h(e2) | ((unsigned)f2h(e3) << 16);
      *(uint2*)(abuf + awoff + j * 2048) = pk;
    }
    // B: linear LDS write
#pragma unroll
    for (int j = 0; j < 4; ++j)
      *(uint4*)(bbuf + j * 4096 + t * 16) = pq[j];

    // prefetch tile it+1 (wraps harmlessly on last iter)
    const int nk = (it + 1) & (ITERS - 1);
#pragma unroll
    for (int j = 0; j < 4; ++j)
      pa[j] = *(const float4*)(asrc + (size_t)j * 16 * NROW + nk * 64);
    const unsigned short* q = qbase + (size_t)nk * 8192;
#pragma unroll
    for (int j = 0; j < 4; ++j)
      pq[j] = *(const uint4*)(q + j * 2048);

    block_sync();

    const f16x8 a0 = *(const f16x8*)(abuf + aro0);
    const f16x8 a1 = *(const f16x8*)(abuf + aro1);
#pragma unroll
    for (int cg = 0; cg < 4; ++cg) {
      const f16x8 b = *(const f16x8*)(bbuf + bro + cg * 512);
      acc[0][cg] = __builtin_amdgcn_mfma_f32_32x32x16_f16(a0, b, acc[0][cg], 0, 0, 0);
      acc[1][cg] = __builtin_amdgcn_mfma_f32_32x32x16_f16(a1, b, acc[1][cg], 0, 0, 0);
    }
  }

  // ---- rowsum partials: reduce 16-lane groups (same wave), one writer each ----
#pragma unroll
  for (int j = 0; j < 4; ++j) {
    float s = rs4[j];
    s += __shfl_xor(s, 1);
    s += __shfl_xor(s, 2);
    s += __shfl_xor(s, 4);
    s += __shfl_xor(s, 8);
    if ((t & 15) == 0)
      rspart[kh * NROW + m0 + j * 16 + (t >> 4)] = s;
  }

  // ---- cross-wave k-reduction of accumulators (8 rounds, reuse B LDS) ----
  __syncthreads();
#pragma unroll
  for (int rg = 0; rg < 2; ++rg) {
#pragma unroll
    for (int cg = 0; cg < 4; ++cg) {
#pragma unroll
      for (int q4 = 0; q4 < 4; ++q4) {
        f32x4 v;
        v[0] = acc[rg][cg][q4 * 4 + 0]; v[1] = acc[rg][cg][q4 * 4 + 1];
        v[2] = acc[rg][cg][q4 * 4 + 2]; v[3] = acc[rg][cg][q4 * 4 + 3];
        *(f32x4*)(smem + 16384 + w * 4096 + l * 64 + q4 * 16) = v;
      }
      __syncthreads();
      if (w == ((rg * 4 + cg) & 3)) {
        float sum[16];
#pragma unroll
        for (int q4 = 0; q4 < 4; ++q4) {
          f32x4 s = *(const f32x4*)(smem + 16384 + 0 * 4096 + l * 64 + q4 * 16);
#pragma unroll
          for (int w2 = 1; w2 < 4; ++w2) {
            const f32x4 v = *(const f32x4*)(smem + 16384 + w2 * 4096 + l * 64 + q4 * 16);
            s[0] += v[0]; s[1] += v[1]; s[2] += v[2]; s[3] += v[3];
          }
          sum[q4 * 4 + 0] = s[0]; sum[q4 * 4 + 1] = s[1];
          sum[q4 * 4 + 2] = s[2]; sum[q4 * 4 + 3] = s[3];
        }
#pragma unroll
        for (int r = 0; r < 16; ++r) {
          const int orow = (r & 3) + 8 * (r >> 2) + 4 * hh;
          ppart[(size_t)kh * NROW * DDIM +
                (m0 + rg * 32 + orow) * (size_t)DDIM + cg * 32 + row_l] = sum[r];
        }
      }
      __syncthreads();
    }
  }
}

// ---------------- combine: out = (p0+p1) / (rs0+rs1) ----------------
__global__ __launch_bounds__(256) void combine(const float* __restrict__ ppart,
                                               const float* __restrict__ rspart,
                                               float* __restrict__ out) {
  const int i = blockIdx.x * 256 + threadIdx.x;  // f32x4 index
  const int row = i >> 5;
  const f32x4 p0 = *(const f32x4*)(ppart + (size_t)i * 4);
  const f32x4 p1 = *(const f32x4*)(ppart + (size_t)NROW * DDIM + (size_t)i * 4);
  const float inv = 1.0f / (rspart[row] + rspart[NROW + row]);
  f32x4 o;
  o[0] = (p0[0] + p1[0]) * inv;
  o[1] = (p0[1] + p1[1]) * inv;
  o[2] = (p0[2] + p1[2]) * inv;
  o[3] = (p0[3] + p1[3]) * inv;
  *(f32x4*)(out + (size_t)i * 4) = o;
}

extern "C" void kernel_launch(void* const* d_in, const int* in_sizes, int n_in,
                              void* d_out, int out_size, void* d_ws, size_t ws_size,
                              hipStream_t stream) {
  (void)in_sizes; (void)n_in; (void)out_size; (void)ws_size;
  const float* h   = (const float*)d_in[0];
  const float* adj = (const float*)d_in[1];
  float* out = (float*)d_out;
  char* ws = (char*)d_ws;
  unsigned short* hq = (unsigned short*)ws;                    // 4 MB
  float* ppart  = (float*)(ws + (size_t)4 * 1024 * 1024);      // 16 MB (2 halves)
  float* rspart = (float*)(ws + (size_t)20 * 1024 * 1024);     // 128 KB

  prep_hq<<<dim3(NROW / 64), dim3(256), 0, stream>>>(h, hq);
  fused<<<dim3(512), dim3(256), 0, stream>>>(adj, hq, ppart, rspart);
  combine<<<dim3(NROW * DDIM / 1024), dim3(256), 0, stream>>>(ppart, rspart, out);
}

// Round 8
// 246.816 us; speedup vs baseline: 1.7627x; 1.7627x over previous
//
#include <hip/hip_runtime.h>

#define NROW 16384
#define DDIM 128

typedef _Float16 f16x8 __attribute__((ext_vector_type(8)));
typedef __fp16 fp16x2 __attribute__((ext_vector_type(2)));
typedef float f32x4 __attribute__((ext_vector_type(4)));

__device__ __forceinline__ unsigned short f2h(float x) {
  union { _Float16 f; unsigned short u; } cvt;
  cvt.f = (_Float16)x;  // RNE
  return cvt.u;
}

__device__ __forceinline__ unsigned pkrtz(float a, float b) {
  union { fp16x2 h; unsigned u; } cvt;
  cvt.h = __builtin_amdgcn_cvt_pkrtz(a, b);  // 1 VALU op: v_cvt_pkrtz_f16_f32
  return cvt.u;
}

// Raw barrier without the compiler's vmcnt(0) drain: lets prefetch loads
// stay in flight across the barrier (m97 barrier-drain workaround).
__device__ __forceinline__ void block_sync() {
  asm volatile("s_waitcnt lgkmcnt(0)" ::: "memory");  // ds_writes done
  __builtin_amdgcn_s_barrier();
  asm volatile("" ::: "memory");                      // no hoisting of reads
}

// ---------------- prep: ht[d][i] = fp16(h[i][d]) ----------------
__global__ __launch_bounds__(256) void prep_ht(const float* __restrict__ h,
                                               unsigned short* __restrict__ ht) {
  __shared__ unsigned short tile[DDIM][65];  // 65: 2-way-free transpose
  const int t = threadIdx.x;
  const int i0 = blockIdx.x * 64;
#pragma unroll
  for (int rep = 0; rep < 8; ++rep) {
    int idx = rep * 256 + t;          // 0..2047 float4s of a 64x128 tile
    int r = idx >> 5, c4 = idx & 31;
    const float4 v = *(const float4*)(h + (size_t)(i0 + r) * DDIM + c4 * 4);
    int c = c4 * 4;
    tile[c + 0][r] = f2h(v.x);
    tile[c + 1][r] = f2h(v.y);
    tile[c + 2][r] = f2h(v.z);
    tile[c + 3][r] = f2h(v.w);
  }
  __syncthreads();
#pragma unroll
  for (int rep = 0; rep < 4; ++rep) {
    int idx = rep * 256 + t;          // 0..1023 groups of 8
    int d = idx >> 3, io = (idx & 7) * 8;
    uint4 o;
    o.x = (unsigned)tile[d][io + 0] | ((unsigned)tile[d][io + 1] << 16);
    o.y = (unsigned)tile[d][io + 2] | ((unsigned)tile[d][io + 3] << 16);
    o.z = (unsigned)tile[d][io + 4] | ((unsigned)tile[d][io + 5] << 16);
    o.w = (unsigned)tile[d][io + 6] | ((unsigned)tile[d][io + 7] << 16);
    *(uint4*)(ht + (size_t)d * NROW + i0 + io) = o;
  }
}

// ---------------- fused: out = rownorm(exp(adj)) @ h ----------------
// R1 skeleton (proven best): BM=32, BK=64, 4 waves (wr,wc), dbuf LDS,
// one raw barrier/iter, reg-staged prefetch in flight across barrier.
// R7 cuts: B-writes-first ordering, pkrtz pack, rowsum via MFMA ones-column
// (kills rowsum VALU + entire shuffle/LDS epilogue), setprio around MFMA.
__global__ __launch_bounds__(256, 2) void fused(const float* __restrict__ adj,
                                                const unsigned short* __restrict__ ht,
                                                float* __restrict__ out) {
  __shared__ __align__(16) char smem[40960];  // A: 2*4KB @0, BT: 2*16KB @8192
  const int t = threadIdx.x;
  const size_t m0 = (size_t)blockIdx.x * 32;

  // --- staging indices (pre-swizzled source chunk) ---
  const int srow = t >> 3;                         // 0..31
  const int chk = (t & 7) ^ (srow & 7);            // semantic 8-elem chunk
  const float* ap = adj + (m0 + srow) * (size_t)NROW + chk * 8;
  const unsigned short* hp = ht + (size_t)srow * NROW + chk * 8;

  // --- mfma indices ---
  const int l = t & 63, w = t >> 6;
  const int wr = w >> 1, wc = w & 1;
  const int lr = l & 15, kg = l >> 4;              // kg: k-group 0..3
  const int arow = wr * 16 + lr;                   // 0..31
  const int aoff0 = arow * 128 + (((kg    ) ^ (arow & 7)) << 4);
  const int aoff1 = arow * 128 + (((kg + 4) ^ (arow & 7)) << 4);
  const int d0 = wc * 64 + lr;                     // d&7 == lr&7 for all cf
  const int boff0 = d0 * 128 + (((kg    ) ^ (lr & 7)) << 4);
  const int boff1 = d0 * 128 + (((kg + 4) ^ (lr & 7)) << 4);

  f32x4 acc[4];
#pragma unroll
  for (int cf = 0; cf < 4; ++cf) acc[cf] = (f32x4){0.f, 0.f, 0.f, 0.f};
  f32x4 rsum = (f32x4){0.f, 0.f, 0.f, 0.f};  // rowsum via ones-column MFMA

  f16x8 ones;
#pragma unroll
  for (int e = 0; e < 8; ++e) ones[e] = (_Float16)1.0f;

  // prefetch tile 0
  float4 pa0 = *(const float4*)(ap);
  float4 pa1 = *(const float4*)(ap + 4);
  uint4 pb0 = *(const uint4*)(hp);
  uint4 pb1 = *(const uint4*)(hp + 32 * NROW);
  uint4 pb2 = *(const uint4*)(hp + 64 * NROW);
  uint4 pb3 = *(const uint4*)(hp + 96 * NROW);

  for (int it = 0; it < NROW / 64; ++it) {
    const int cur = it & 1;

    // 1. B LDS writes first (independent of exp -> overlaps VALU chain)
    uint4* bb = (uint4*)(smem + 8192 + cur * 16384);
    bb[t] = pb0; bb[t + 256] = pb1; bb[t + 512] = pb2; bb[t + 768] = pb3;

    // 2. issue B prefetch for t+1 (regs free after step 1)
    const float4 a0 = pa0, a1 = pa1;
    if (it + 1 < NROW / 64) {
      const unsigned short* hb = hp + (it + 1) * 64;
      pb0 = *(const uint4*)(hb);
      pb1 = *(const uint4*)(hb + 32 * NROW);
      pb2 = *(const uint4*)(hb + 64 * NROW);
      pb3 = *(const uint4*)(hb + 96 * NROW);
    }

    // 3. exp + pkrtz pack (no rowsum adds here anymore)
    uint4 aw;
    aw.x = pkrtz(__expf(a0.x), __expf(a0.y));
    aw.y = pkrtz(__expf(a0.z), __expf(a0.w));
    aw.z = pkrtz(__expf(a1.x), __expf(a1.y));
    aw.w = pkrtz(__expf(a1.z), __expf(a1.w));

    // 4. A LDS write + A prefetch
    *(uint4*)(smem + cur * 4096 + t * 16) = aw;
    if (it + 1 < NROW / 64) {
      const float* a = ap + (it + 1) * 64;
      pa0 = *(const float4*)(a);
      pa1 = *(const float4*)(a + 4);
    }

    // 5. barrier (LDS visible; global prefetch stays in flight)
    block_sync();

    // 6. fragments + MFMA (rowsum folded in via ones-column)
    const char* aB = smem + cur * 4096;
    const char* bB = smem + 8192 + cur * 16384;
    __builtin_amdgcn_s_setprio(1);
    f16x8 af0 = *(const f16x8*)(aB + aoff0);
    f16x8 af1 = *(const f16x8*)(aB + aoff1);
    rsum = __builtin_amdgcn_mfma_f32_16x16x32_f16(af0, ones, rsum, 0, 0, 0);
#pragma unroll
    for (int cf = 0; cf < 4; ++cf) {
      f16x8 bf0 = *(const f16x8*)(bB + boff0 + cf * 2048);
      acc[cf] = __builtin_amdgcn_mfma_f32_16x16x32_f16(af0, bf0, acc[cf], 0, 0, 0);
    }
    rsum = __builtin_amdgcn_mfma_f32_16x16x32_f16(af1, ones, rsum, 0, 0, 0);
#pragma unroll
    for (int cf = 0; cf < 4; ++cf) {
      f16x8 bf1 = *(const f16x8*)(bB + boff1 + cf * 2048);
      acc[cf] = __builtin_amdgcn_mfma_f32_16x16x32_f16(af1, bf1, acc[cf], 0, 0, 0);
    }
    __builtin_amdgcn_s_setprio(0);
  }

  // epilogue: D[(kg*4+r)][lr]; rsum[r] holds this lane's row's sum
  // (every D column of the ones-MFMA equals the rowsum), no sync needed.
#pragma unroll
  for (int r = 0; r < 4; ++r) {
    const int row_l = wr * 16 + kg * 4 + r;
    const float inv = 1.0f / rsum[r];
    float* orow = out + (m0 + row_l) * (size_t)DDIM + wc * 64 + lr;
#pragma unroll
    for (int cf = 0; cf < 4; ++cf) {
      orow[cf * 16] = acc[cf][r] * inv;
    }
  }
}

extern "C" void kernel_launch(void* const* d_in, const int* in_sizes, int n_in,
                              void* d_out, int out_size, void* d_ws, size_t ws_size,
                              hipStream_t stream) {
  (void)in_sizes; (void)n_in; (void)out_size; (void)ws_size;
  const float* h   = (const float*)d_in[0];
  const float* adj = (const float*)d_in[1];
  float* out = (float*)d_out;
  unsigned short* ht = (unsigned short*)d_ws;  // 128*16384 fp16 = 4 MB

  prep_ht<<<dim3(NROW / 64), dim3(256), 0, stream>>>(h, ht);
  fused<<<dim3(NROW / 32), dim3(256), 0, stream>>>(adj, ht, out);
}